// Round 6
// baseline (554.782 us; speedup 1.0000x reference)
//
#include <hip/hip_runtime.h>
#include <cstdint>
#include <cstddef>

#define B_  2
#define S_  2048
#define H_  768
#define NH  12
#define DH  64
#define RD  5
#define BN  (B_*NH)   // 24

typedef _Float16 f16;
typedef __attribute__((ext_vector_type(8))) _Float16 f16x8;
typedef __attribute__((ext_vector_type(4))) float f32x4;

#define MFMA16(a, b, c) __builtin_amdgcn_mfma_f32_16x16x32_f16((a), (b), (c), 0, 0, 0)

#if __has_builtin(__builtin_amdgcn_exp2f)
__device__ __forceinline__ float exp2fast(float x) { return __builtin_amdgcn_exp2f(x); }
#else
__device__ __forceinline__ float exp2fast(float x) { return __expf(0.69314718056f * x); }
#endif

#define SCL 0.1803368801f   /* 0.125 * log2(e) */
#define L2E 1.44269504f

#define NX4 ((B_*S_*H_)/4)   // 786432
#define NW4 ((H_*H_)/4)      // 147456

// ---------------------------------------------------------------------------
// Kernel 0: fused fp32 -> fp16 conversion of x, Wq, Wk, Wv (one launch).
// ---------------------------------------------------------------------------
__global__ __launch_bounds__(256) void cvtall(
    const float* __restrict__ x,
    const float* __restrict__ wq, const float* __restrict__ wk,
    const float* __restrict__ wv,
    f16* __restrict__ xh, f16* __restrict__ wh)
{
    int idx = blockIdx.x * 256 + threadIdx.x;
    const int total4 = NX4 + 3 * NW4;
    if (idx >= total4) return;
    const float* src;
    f16* dst;
    int off;
    if (idx < NX4) {
        src = x; dst = xh; off = idx;
    } else {
        int r = idx - NX4;
        int which = r / NW4;
        off = r - which * NW4;
        src = (which == 0) ? wq : (which == 1) ? wk : wv;
        dst = wh + (size_t)which * H_ * H_;
    }
    float4 f = ((const float4*)src)[off];
    f16 h[4] = {(f16)f.x, (f16)f.y, (f16)f.z, (f16)f.w};
    ((ushort4*)dst)[off] = *(const ushort4*)h;
}

// ---------------------------------------------------------------------------
// Kernel 1: MFMA QKV projection (fp16 in/out).  One block: 64 rows x 64 cols
// of q,k,v (same x tile, three W tiles).  V written transposed vt[bn][d][s].
// grid (12, 64).
// ---------------------------------------------------------------------------
__global__ __launch_bounds__(256, 3) void qkv_gemm(
    const f16* __restrict__ xh, const f16* __restrict__ wh,
    const float* __restrict__ bq, const float* __restrict__ bk,
    const float* __restrict__ bv,
    f16* __restrict__ qo, f16* __restrict__ ko, f16* __restrict__ vt)
{
    __shared__ __align__(16) f16 Xs[64][72];
    __shared__ __align__(16) f16 Ws[3][64][72];

    const int tid = threadIdx.x;
    const int n  = blockIdx.x;          // head / 64-col tile
    const int m0 = blockIdx.y * 64;
    const int w = tid >> 6, lane = tid & 63;
    const int l15 = lane & 15, quad = lane >> 4;
    const int srow = tid >> 2, sc0 = (tid & 3) * 16;

    f32x4 acc[3][4];
#pragma unroll
    for (int i = 0; i < 3; ++i)
#pragma unroll
        for (int ns = 0; ns < 4; ++ns) acc[i][ns] = (f32x4){0.f, 0.f, 0.f, 0.f};

    const f16* xsrc = xh + (size_t)(m0 + srow) * H_ + sc0;
    const f16* wsrc = wh + (size_t)(n * 64 + srow) * H_ + sc0;

    for (int kc = 0; kc < 12; ++kc) {
        __syncthreads();
        {
            const f16* s0 = xsrc + kc * 64;
            *(f16x8*)&Xs[srow][sc0]     = *(const f16x8*)(s0);
            *(f16x8*)&Xs[srow][sc0 + 8] = *(const f16x8*)(s0 + 8);
        }
#pragma unroll
        for (int i = 0; i < 3; ++i) {
            const f16* s0 = wsrc + (size_t)i * H_ * H_ + kc * 64;
            *(f16x8*)&Ws[i][srow][sc0]     = *(const f16x8*)(s0);
            *(f16x8*)&Ws[i][srow][sc0 + 8] = *(const f16x8*)(s0 + 8);
        }
        __syncthreads();

        f16x8 a0 = *(const f16x8*)&Xs[w * 16 + l15][quad * 8];
        f16x8 a1 = *(const f16x8*)&Xs[w * 16 + l15][quad * 8 + 32];
#pragma unroll
        for (int i = 0; i < 3; ++i)
#pragma unroll
            for (int ns = 0; ns < 4; ++ns) {
                f16x8 b0 = *(const f16x8*)&Ws[i][ns * 16 + l15][quad * 8];
                f16x8 b1 = *(const f16x8*)&Ws[i][ns * 16 + l15][quad * 8 + 32];
                acc[i][ns] = MFMA16(a0, b0, acc[i][ns]);
                acc[i][ns] = MFMA16(a1, b1, acc[i][ns]);
            }
    }
    __syncthreads();

    const float* bias[3] = {bq, bk, bv};
    f16 (*T0)[72] = Xs;      // q
    f16 (*T1)[72] = Ws[0];   // k
    f16 (*T2)[72] = Ws[1];   // v
#pragma unroll
    for (int i = 0; i < 3; ++i) {
        f16 (*T)[72] = (i == 0) ? T0 : (i == 1) ? T1 : T2;
#pragma unroll
        for (int ns = 0; ns < 4; ++ns) {
            float bb = bias[i][n * 64 + ns * 16 + l15];
#pragma unroll
            for (int reg = 0; reg < 4; ++reg)
                T[w * 16 + quad * 4 + reg][ns * 16 + l15] =
                    (f16)(acc[i][ns][reg] + bb);
        }
    }
    __syncthreads();

    const int mrow = m0 + srow;
    const int bb2 = mrow >> 11, ss = mrow & 2047;
    {
        f16* dst = qo + ((size_t)(bb2 * NH + n) * S_ + ss) * DH + sc0;
        *(f16x8*)dst       = *(const f16x8*)&T0[srow][sc0];
        *(f16x8*)(dst + 8) = *(const f16x8*)&T0[srow][sc0 + 8];
    }
    {
        f16* dst = ko + ((size_t)(bb2 * NH + n) * S_ + ss) * DH + sc0;
        *(f16x8*)dst       = *(const f16x8*)&T1[srow][sc0];
        *(f16x8*)(dst + 8) = *(const f16x8*)&T1[srow][sc0 + 8];
    }
    {
        f16 tmp[16];
#pragma unroll
        for (int u = 0; u < 16; ++u) tmp[u] = T2[sc0 + u][srow];
        f16* dst = vt + ((size_t)(bb2 * NH + n) * DH + srow) * S_ + (m0 & 2047) + sc0;
        *(f16x8*)dst       = *(const f16x8*)&tmp[0];
        *(f16x8*)(dst + 8) = *(const f16x8*)&tmp[8];
    }
}

// ---------------------------------------------------------------------------
// Kernel 2: pack binary adjacency -> bytes, i-quad interleaved.
// ---------------------------------------------------------------------------
__global__ __launch_bounds__(256) void adjpack(
    const float* __restrict__ adj, unsigned char* __restrict__ adjp)
{
    const int idx = blockIdx.x * 256 + threadIdx.x;   // [0, 2^21)
    const int j  = idx & 2047;
    const int iq = (idx >> 11) & 511;
    const int b  = idx >> 20;
    unsigned int bits[4] = {0, 0, 0, 0};
#pragma unroll
    for (int r = 0; r < RD; ++r) {
#pragma unroll
        for (int ii = 0; ii < 4; ++ii) {
            float a = adj[(((size_t)(r * B_ + b) * S_) + iq * 4 + ii) * S_ + j];
            bits[ii] |= (a != 0.f ? 1u : 0u) << r;
        }
    }
    uchar4 pk;
    pk.x = (unsigned char)bits[0];
    pk.y = (unsigned char)bits[1];
    pk.z = (unsigned char)bits[2];
    pk.w = (unsigned char)bits[3];
    *(uchar4*)(adjp + (size_t)idx * 4) = pk;
}

// ---------------------------------------------------------------------------
// Kernel 3: MFMA flash attention, j-split across wave pairs.
// Block = (bn, 32-row i-tile); waves 0,1: 16 rows each, j in [0,1024);
// waves 2,3: same rows, j in [1024,2048).  Merge states in LDS at end.
// grid (24, 64) = 1536 blocks -> 6 blocks/CU; VGPR ~80 -> ~6 waves/SIMD.
// launch_bounds(256,3): 170-reg budget, measured spill-free at this body.
// ((256,4) forced spills in round 4 -- do not tighten.)
// ---------------------------------------------------------------------------
__global__ __launch_bounds__(256, 3) void attn(
    const f16* __restrict__ q, const f16* __restrict__ k, const f16* __restrict__ vt,
    const float* __restrict__ bili, const unsigned char* __restrict__ adjp,
    const float* __restrict__ mask, const float* __restrict__ absb,
    float* __restrict__ out)
{
    __shared__ __align__(16) char smem[12800 + 9216 + 128];
    f16*   Mt  = (f16*)smem;                     // [64][72]  (prologue only)
    float* Mg  = (float*)smem;                   // [2][64][25] (merge, reuses Mt)
    f16*   Pb  = (f16*)(smem + 12800);           // [4][16][72]
    float* lut = (float*)(smem + 12800 + 9216);  // [32]

    const int tid = threadIdx.x;
    const int bn = blockIdx.x, it = blockIdx.y;
    const int b = bn / NH, n = bn % NH;
    const int w = tid >> 6, lane = tid & 63;
    const int l15 = lane & 15, quad = lane >> 4;
    const int wrow = w & 1, half = w >> 1;
    const int wi0 = it * 32 + wrow * 16;
    const size_t kbase = (size_t)bn * S_ * DH;

    if (tid < 32) {
        float a = 0.f;
#pragma unroll
        for (int r = 0; r < RD; ++r)
            if (tid & (1 << r)) a += absb[r * NH + n];
        lut[tid] = a * SCL;
    }

    const f16* qrow = q + kbase + (size_t)(wi0 + l15) * DH + quad * 8;
    f16x8 aq0 = *(const f16x8*)(qrow);
    f16x8 aq1 = *(const f16x8*)(qrow + 32);

    f16* Pw = Pb + w * 16 * 72;

    // ---- build Q'_r A-frags via MFMA (M_r staged transposed in LDS) ----
    f16x8 aqp[RD][2];
#pragma unroll 1
    for (int r = 0; r < RD; ++r) {
        __syncthreads();
        {
            int p = tid >> 2, q0 = (tid & 3) * 16;
            const float* src = bili + ((size_t)(r * NH + n) * DH + p) * DH + q0;
            float4 g0 = ((const float4*)src)[0];
            float4 g1 = ((const float4*)src)[1];
            float4 g2 = ((const float4*)src)[2];
            float4 g3 = ((const float4*)src)[3];
            float mv[16] = {g0.x, g0.y, g0.z, g0.w, g1.x, g1.y, g1.z, g1.w,
                            g2.x, g2.y, g2.z, g2.w, g3.x, g3.y, g3.z, g3.w};
#pragma unroll
            for (int u = 0; u < 16; ++u) Mt[(q0 + u) * 72 + p] = (f16)mv[u];
        }
        __syncthreads();
#pragma unroll
        for (int ns = 0; ns < 4; ++ns) {
            f16x8 b0 = *(const f16x8*)&Mt[(ns * 16 + l15) * 72 + quad * 8];
            f16x8 b1 = *(const f16x8*)&Mt[(ns * 16 + l15) * 72 + quad * 8 + 32];
            f32x4 d = {0.f, 0.f, 0.f, 0.f};
            d = MFMA16(aq0, b0, d);
            d = MFMA16(aq1, b1, d);
#pragma unroll
            for (int reg = 0; reg < 4; ++reg)
                Pw[(quad * 4 + reg) * 72 + ns * 16 + l15] = (f16)d[reg];
        }
        aqp[r][0] = *(const f16x8*)&Pw[l15 * 72 + quad * 8];
        aqp[r][1] = *(const f16x8*)&Pw[l15 * 72 + quad * 8 + 32];
    }
    __syncthreads();   // Mt dead; Mg written after j-loop

    f16x8 ones;
#pragma unroll
    for (int u = 0; u < 8; ++u) ones[u] = (f16)1.0f;

    f32x4 o[4] = {{0,0,0,0},{0,0,0,0},{0,0,0,0},{0,0,0,0}};
    f32x4 lacc = {0.f, 0.f, 0.f, 0.f};
    float mrun[4] = {-1e30f, -1e30f, -1e30f, -1e30f};

    const unsigned char* adjrow =
        adjp + (size_t)(b * 512 + (wi0 >> 2) + quad) * (S_ * 4);
    const float* maskrow = mask + (size_t)b * S_;
    const f16* vtb = vt + (size_t)bn * DH * S_;

    for (int t = 0; t < 16; ++t) {
        const int j0 = half * 1024 + t * 64;
        float sc[4][4];

#pragma unroll
        for (int js = 0; js < 4; ++js) {
            const int jcol = j0 + js * 16 + l15;
            const f16* kp = k + kbase + (size_t)jcol * DH + quad * 8;
            f16x8 bk0 = *(const f16x8*)(kp);
            f16x8 bk1 = *(const f16x8*)(kp + 32);

            f32x4 aqk = {0.f, 0.f, 0.f, 0.f};
            aqk = MFMA16(aq0, bk0, aqk);
            aqk = MFMA16(aq1, bk1, aqk);
            f32x4 ar[RD];
#pragma unroll
            for (int r = 0; r < RD; ++r) {
                f32x4 z = {0.f, 0.f, 0.f, 0.f};
                z = MFMA16(aqp[r][0], bk0, z);
                z = MFMA16(aqp[r][1], bk1, z);
                ar[r] = z;
            }

            uchar4 a4 = *(const uchar4*)(adjrow + (size_t)jcol * 4);
            unsigned int bbits[4] = {a4.x, a4.y, a4.z, a4.w};
            float mkL = maskrow[jcol] * L2E;
#pragma unroll
            for (int reg = 0; reg < 4; ++reg) {
                float s = aqk[reg];
                unsigned int bt = bbits[reg];
#pragma unroll
                for (int r = 0; r < RD; ++r)
                    s = fmaf((float)((bt >> r) & 1u), ar[r][reg], s);
                sc[js][reg] = fmaf(s, SCL, lut[bt] + mkL);
            }
        }

        // ---- online softmax (exp2 domain; rows in 16-lane groups) ----
        float alpha[4];
#pragma unroll
        for (int reg = 0; reg < 4; ++reg) {
            float nm = fmaxf(fmaxf(sc[0][reg], sc[1][reg]),
                             fmaxf(sc[2][reg], sc[3][reg]));
#pragma unroll
            for (int off = 1; off < 16; off <<= 1)
                nm = fmaxf(nm, __shfl_xor(nm, off));
            float mn = fmaxf(mrun[reg], nm);
            alpha[reg] = exp2fast(mrun[reg] - mn);
            mrun[reg] = mn;
        }
#pragma unroll
        for (int js = 0; js < 4; ++js)
#pragma unroll
            for (int reg = 0; reg < 4; ++reg) {
                float p = exp2fast(sc[js][reg] - mrun[reg]);
                Pw[(quad * 4 + reg) * 72 + js * 16 + l15] = (f16)p;
            }
#pragma unroll
        for (int reg = 0; reg < 4; ++reg) {
            lacc[reg] *= alpha[reg];
#pragma unroll
            for (int ds = 0; ds < 4; ++ds) o[ds][reg] *= alpha[reg];
        }

        // ---- PV + row-sum via MFMA ----
        f16x8 pa0 = *(const f16x8*)&Pw[l15 * 72 + quad * 8];
        f16x8 pa1 = *(const f16x8*)&Pw[l15 * 72 + quad * 8 + 32];
        lacc = MFMA16(pa0, ones, lacc);
        lacc = MFMA16(pa1, ones, lacc);
#pragma unroll
        for (int ds = 0; ds < 4; ++ds) {
            const f16* vp = vtb + (size_t)(ds * 16 + l15) * S_ + j0 + quad * 8;
            f16x8 bv0 = *(const f16x8*)(vp);
            f16x8 bv1 = *(const f16x8*)(vp + 32);
            o[ds] = MFMA16(pa0, bv0, o[ds]);
            o[ds] = MFMA16(pa1, bv1, o[ds]);
        }
    }

    // ---- merge j-halves ----
    if (half == 1) {
        float* g = Mg + ((size_t)wrow * 64 + lane) * 25;
#pragma unroll
        for (int ds = 0; ds < 4; ++ds)
#pragma unroll
            for (int reg = 0; reg < 4; ++reg) g[ds * 4 + reg] = o[ds][reg];
#pragma unroll
        for (int reg = 0; reg < 4; ++reg) {
            g[16 + reg] = lacc[reg];
            g[20 + reg] = mrun[reg];
        }
    }
    __syncthreads();
    if (half == 0) {
        const float* g = Mg + ((size_t)wrow * 64 + lane) * 25;
#pragma unroll
        for (int reg = 0; reg < 4; ++reg) {
            float m1 = g[20 + reg];
            float mm = fmaxf(mrun[reg], m1);
            float fa = exp2fast(mrun[reg] - mm);
            float fb = exp2fast(m1 - mm);
            float l = lacc[reg] * fa + g[16 + reg] * fb;
            float inv = 1.f / l;
            int i = wi0 + quad * 4 + reg;
#pragma unroll
            for (int ds = 0; ds < 4; ++ds) {
                float ov = o[ds][reg] * fa + g[ds * 4 + reg] * fb;
                out[((size_t)b * S_ + i) * H_ + n * DH + ds * 16 + l15] = ov * inv;
            }
        }
    }
}

// ---------------------------------------------------------------------------
extern "C" void kernel_launch(void* const* d_in, const int* in_sizes, int n_in,
                              void* d_out, int out_size, void* d_ws, size_t ws_size,
                              hipStream_t stream)
{
    const float* hs   = (const float*)d_in[0];
    const float* mask = (const float*)d_in[1];
    const float* adj  = (const float*)d_in[2];
    const float* Wq   = (const float*)d_in[3];
    const float* bq   = (const float*)d_in[4];
    const float* Wk   = (const float*)d_in[5];
    const float* bk   = (const float*)d_in[6];
    const float* Wv   = (const float*)d_in[7];
    const float* bv   = (const float*)d_in[8];
    const float* bili = (const float*)d_in[9];
    const float* absb = (const float*)d_in[10];
    float* out = (float*)d_out;

    const size_t QKV = (size_t)BN * S_ * DH;       // 3.1M elems
    f16* q  = (f16*)d_ws;
    f16* k  = q + QKV;
    f16* vt = k + QKV;
    unsigned char* adjp = (unsigned char*)(vt + QKV);       // 8 MB
    f16* xh = (f16*)(adjp + (size_t)B_ * 512 * S_ * 4);
    f16* wh = xh + (size_t)B_ * S_ * H_;                    // Wq|Wk|Wv f16

    const int total4 = NX4 + 3 * NW4;
    cvtall<<<(total4 + 255) / 256, 256, 0, stream>>>(hs, Wq, Wk, Wv, xh, wh);
    qkv_gemm<<<dim3(12, 64), 256, 0, stream>>>(xh, wh, bq, bk, bv, q, k, vt);
    adjpack<<<8192, 256, 0, stream>>>(adj, adjp);
    attn<<<dim3(BN, 64), 256, 0, stream>>>(q, k, vt, bili, adjp, mask, absb, out);
}

// Round 7
// 520.912 us; speedup vs baseline: 1.0650x; 1.0650x over previous
//
#include <hip/hip_runtime.h>
#include <cstdint>
#include <cstddef>

#define B_  2
#define S_  2048
#define H_  768
#define NH  12
#define DH  64
#define RD  5
#define BN  (B_*NH)   // 24

typedef _Float16 f16;
typedef __attribute__((ext_vector_type(8))) _Float16 f16x8;
typedef __attribute__((ext_vector_type(4))) float f32x4;

#define MFMA16(a, b, c) __builtin_amdgcn_mfma_f32_16x16x32_f16((a), (b), (c), 0, 0, 0)

#if __has_builtin(__builtin_amdgcn_exp2f)
__device__ __forceinline__ float exp2fast(float x) { return __builtin_amdgcn_exp2f(x); }
#else
__device__ __forceinline__ float exp2fast(float x) { return __expf(0.69314718056f * x); }
#endif

#define SCL 0.1803368801f   /* 0.125 * log2(e) */
#define L2E 1.44269504f

#define NX4 ((B_*S_*H_)/4)   // 786432
#define NW4 ((H_*H_)/4)      // 147456

// ---------------------------------------------------------------------------
// Kernel 0: fused fp32 -> fp16 conversion of x, Wq, Wk, Wv (one launch).
// ---------------------------------------------------------------------------
__global__ __launch_bounds__(256) void cvtall(
    const float* __restrict__ x,
    const float* __restrict__ wq, const float* __restrict__ wk,
    const float* __restrict__ wv,
    f16* __restrict__ xh, f16* __restrict__ wh)
{
    int idx = blockIdx.x * 256 + threadIdx.x;
    const int total4 = NX4 + 3 * NW4;
    if (idx >= total4) return;
    const float* src;
    f16* dst;
    int off;
    if (idx < NX4) {
        src = x; dst = xh; off = idx;
    } else {
        int r = idx - NX4;
        int which = r / NW4;
        off = r - which * NW4;
        src = (which == 0) ? wq : (which == 1) ? wk : wv;
        dst = wh + (size_t)which * H_ * H_;
    }
    float4 f = ((const float4*)src)[off];
    f16 h[4] = {(f16)f.x, (f16)f.y, (f16)f.z, (f16)f.w};
    ((ushort4*)dst)[off] = *(const ushort4*)h;
}

// ---------------------------------------------------------------------------
// Kernel 1: MFMA QKV projection (fp16 in/out).  One block: 64 rows x 64 cols
// of q,k,v (same x tile, three W tiles).  V written transposed vt[bn][d][s].
// grid (12, 64).
// ---------------------------------------------------------------------------
__global__ __launch_bounds__(256, 3) void qkv_gemm(
    const f16* __restrict__ xh, const f16* __restrict__ wh,
    const float* __restrict__ bq, const float* __restrict__ bk,
    const float* __restrict__ bv,
    f16* __restrict__ qo, f16* __restrict__ ko, f16* __restrict__ vt)
{
    __shared__ __align__(16) f16 Xs[64][72];
    __shared__ __align__(16) f16 Ws[3][64][72];

    const int tid = threadIdx.x;
    const int n  = blockIdx.x;          // head / 64-col tile
    const int m0 = blockIdx.y * 64;
    const int w = tid >> 6, lane = tid & 63;
    const int l15 = lane & 15, quad = lane >> 4;
    const int srow = tid >> 2, sc0 = (tid & 3) * 16;

    f32x4 acc[3][4];
#pragma unroll
    for (int i = 0; i < 3; ++i)
#pragma unroll
        for (int ns = 0; ns < 4; ++ns) acc[i][ns] = (f32x4){0.f, 0.f, 0.f, 0.f};

    const f16* xsrc = xh + (size_t)(m0 + srow) * H_ + sc0;
    const f16* wsrc = wh + (size_t)(n * 64 + srow) * H_ + sc0;

    for (int kc = 0; kc < 12; ++kc) {
        __syncthreads();
        {
            const f16* s0 = xsrc + kc * 64;
            *(f16x8*)&Xs[srow][sc0]     = *(const f16x8*)(s0);
            *(f16x8*)&Xs[srow][sc0 + 8] = *(const f16x8*)(s0 + 8);
        }
#pragma unroll
        for (int i = 0; i < 3; ++i) {
            const f16* s0 = wsrc + (size_t)i * H_ * H_ + kc * 64;
            *(f16x8*)&Ws[i][srow][sc0]     = *(const f16x8*)(s0);
            *(f16x8*)&Ws[i][srow][sc0 + 8] = *(const f16x8*)(s0 + 8);
        }
        __syncthreads();

        f16x8 a0 = *(const f16x8*)&Xs[w * 16 + l15][quad * 8];
        f16x8 a1 = *(const f16x8*)&Xs[w * 16 + l15][quad * 8 + 32];
#pragma unroll
        for (int i = 0; i < 3; ++i)
#pragma unroll
            for (int ns = 0; ns < 4; ++ns) {
                f16x8 b0 = *(const f16x8*)&Ws[i][ns * 16 + l15][quad * 8];
                f16x8 b1 = *(const f16x8*)&Ws[i][ns * 16 + l15][quad * 8 + 32];
                acc[i][ns] = MFMA16(a0, b0, acc[i][ns]);
                acc[i][ns] = MFMA16(a1, b1, acc[i][ns]);
            }
    }
    __syncthreads();

    const float* bias[3] = {bq, bk, bv};
    f16 (*T0)[72] = Xs;      // q
    f16 (*T1)[72] = Ws[0];   // k
    f16 (*T2)[72] = Ws[1];   // v
#pragma unroll
    for (int i = 0; i < 3; ++i) {
        f16 (*T)[72] = (i == 0) ? T0 : (i == 1) ? T1 : T2;
#pragma unroll
        for (int ns = 0; ns < 4; ++ns) {
            float bb = bias[i][n * 64 + ns * 16 + l15];
#pragma unroll
            for (int reg = 0; reg < 4; ++reg)
                T[w * 16 + quad * 4 + reg][ns * 16 + l15] =
                    (f16)(acc[i][ns][reg] + bb);
        }
    }
    __syncthreads();

    const int mrow = m0 + srow;
    const int bb2 = mrow >> 11, ss = mrow & 2047;
    {
        f16* dst = qo + ((size_t)(bb2 * NH + n) * S_ + ss) * DH + sc0;
        *(f16x8*)dst       = *(const f16x8*)&T0[srow][sc0];
        *(f16x8*)(dst + 8) = *(const f16x8*)&T0[srow][sc0 + 8];
    }
    {
        f16* dst = ko + ((size_t)(bb2 * NH + n) * S_ + ss) * DH + sc0;
        *(f16x8*)dst       = *(const f16x8*)&T1[srow][sc0];
        *(f16x8*)(dst + 8) = *(const f16x8*)&T1[srow][sc0 + 8];
    }
    {
        f16 tmp[16];
#pragma unroll
        for (int u = 0; u < 16; ++u) tmp[u] = T2[sc0 + u][srow];
        f16* dst = vt + ((size_t)(bb2 * NH + n) * DH + srow) * S_ + (m0 & 2047) + sc0;
        *(f16x8*)dst       = *(const f16x8*)&tmp[0];
        *(f16x8*)(dst + 8) = *(const f16x8*)&tmp[8];
    }
}

// ---------------------------------------------------------------------------
// Kernel 2: pack binary adjacency -> bytes, i-quad interleaved.
// ---------------------------------------------------------------------------
__global__ __launch_bounds__(256) void adjpack(
    const float* __restrict__ adj, unsigned char* __restrict__ adjp)
{
    const int idx = blockIdx.x * 256 + threadIdx.x;   // [0, 2^21)
    const int j  = idx & 2047;
    const int iq = (idx >> 11) & 511;
    const int b  = idx >> 20;
    unsigned int bits[4] = {0, 0, 0, 0};
#pragma unroll
    for (int r = 0; r < RD; ++r) {
#pragma unroll
        for (int ii = 0; ii < 4; ++ii) {
            float a = adj[(((size_t)(r * B_ + b) * S_) + iq * 4 + ii) * S_ + j];
            bits[ii] |= (a != 0.f ? 1u : 0u) << r;
        }
    }
    uchar4 pk;
    pk.x = (unsigned char)bits[0];
    pk.y = (unsigned char)bits[1];
    pk.z = (unsigned char)bits[2];
    pk.w = (unsigned char)bits[3];
    *(uchar4*)(adjp + (size_t)idx * 4) = pk;
}

// ---------------------------------------------------------------------------
// Kernel 3: MFMA flash attention.  1-D grid of 768 blocks, XCD-swizzled:
//   g = idx & 7, it = (idx >> 3) & 31, bn = 8*(idx >> 8) + g
// -> all 32 i-tile blocks of a bn share idx%8, i.e. (heuristically) one XCD,
//    so that bn's K/V (~1 MB) stays L2-resident instead of thrashing L3.
// Block: 4 waves, each wave owns 16 rows and the FULL j range; no barriers
// in the j-loop.  Occupancy is register-capped at 3 waves/SIMD (~160 total
// arch+acc regs) -- launch_bounds(256,3) measured spill-free; (256,4) spills.
// ---------------------------------------------------------------------------
__global__ __launch_bounds__(256, 3) void attn(
    const f16* __restrict__ q, const f16* __restrict__ k, const f16* __restrict__ vt,
    const float* __restrict__ bili, const unsigned char* __restrict__ adjp,
    const float* __restrict__ mask, const float* __restrict__ absb,
    float* __restrict__ out)
{
    __shared__ __align__(16) char smem[9216 + 9216 + 128];
    f16*   Mt  = (f16*)smem;                    // [64][72] (prologue only)
    f16*   Pb  = (f16*)(smem + 9216);           // [4][16][72]
    float* lut = (float*)(smem + 9216 + 9216);  // [32]

    const int tid = threadIdx.x;
    const int idx = blockIdx.x;
    const int g = idx & 7;
    const int it = (idx >> 3) & 31;
    const int bn = 8 * (idx >> 8) + g;
    const int b = bn / NH, n = bn % NH;
    const int w = tid >> 6, lane = tid & 63;
    const int l15 = lane & 15, quad = lane >> 4;
    const int wi0 = it * 64 + w * 16;
    const size_t kbase = (size_t)bn * S_ * DH;

    if (tid < 32) {
        float a = 0.f;
#pragma unroll
        for (int r = 0; r < RD; ++r)
            if (tid & (1 << r)) a += absb[r * NH + n];
        lut[tid] = a * SCL;
    }

    const f16* qrow = q + kbase + (size_t)(wi0 + l15) * DH + quad * 8;
    f16x8 aq0 = *(const f16x8*)(qrow);
    f16x8 aq1 = *(const f16x8*)(qrow + 32);

    f16* Pw = Pb + w * 16 * 72;

    // ---- build Q'_r A-frags via MFMA (M_r staged transposed in LDS) ----
    f16x8 aqp[RD][2];
#pragma unroll 1
    for (int r = 0; r < RD; ++r) {
        __syncthreads();
        {
            int p = tid >> 2, q0 = (tid & 3) * 16;
            const float* src = bili + ((size_t)(r * NH + n) * DH + p) * DH + q0;
            float4 g0 = ((const float4*)src)[0];
            float4 g1 = ((const float4*)src)[1];
            float4 g2 = ((const float4*)src)[2];
            float4 g3 = ((const float4*)src)[3];
            float mv[16] = {g0.x, g0.y, g0.z, g0.w, g1.x, g1.y, g1.z, g1.w,
                            g2.x, g2.y, g2.z, g2.w, g3.x, g3.y, g3.z, g3.w};
#pragma unroll
            for (int u = 0; u < 16; ++u) Mt[(q0 + u) * 72 + p] = (f16)mv[u];
        }
        __syncthreads();
#pragma unroll
        for (int ns = 0; ns < 4; ++ns) {
            f16x8 b0 = *(const f16x8*)&Mt[(ns * 16 + l15) * 72 + quad * 8];
            f16x8 b1 = *(const f16x8*)&Mt[(ns * 16 + l15) * 72 + quad * 8 + 32];
            f32x4 d = {0.f, 0.f, 0.f, 0.f};
            d = MFMA16(aq0, b0, d);
            d = MFMA16(aq1, b1, d);
#pragma unroll
            for (int reg = 0; reg < 4; ++reg)
                Pw[(quad * 4 + reg) * 72 + ns * 16 + l15] = (f16)d[reg];
        }
        aqp[r][0] = *(const f16x8*)&Pw[l15 * 72 + quad * 8];
        aqp[r][1] = *(const f16x8*)&Pw[l15 * 72 + quad * 8 + 32];
    }

    f16x8 ones;
#pragma unroll
    for (int u = 0; u < 8; ++u) ones[u] = (f16)1.0f;

    f32x4 o[4] = {{0,0,0,0},{0,0,0,0},{0,0,0,0},{0,0,0,0}};
    f32x4 lacc = {0.f, 0.f, 0.f, 0.f};
    float mrun[4] = {-1e30f, -1e30f, -1e30f, -1e30f};

    const unsigned char* adjrow =
        adjp + (size_t)(b * 512 + (wi0 >> 2) + quad) * (S_ * 4);
    const float* maskrow = mask + (size_t)b * S_;
    const f16* vtb = vt + (size_t)bn * DH * S_;

    for (int t = 0; t < 32; ++t) {
        const int j0 = t * 64;
        float sc[4][4];

#pragma unroll
        for (int js = 0; js < 4; ++js) {
            const int jcol = j0 + js * 16 + l15;
            const f16* kp = k + kbase + (size_t)jcol * DH + quad * 8;
            f16x8 bk0 = *(const f16x8*)(kp);
            f16x8 bk1 = *(const f16x8*)(kp + 32);

            f32x4 aqk = {0.f, 0.f, 0.f, 0.f};
            aqk = MFMA16(aq0, bk0, aqk);
            aqk = MFMA16(aq1, bk1, aqk);
            f32x4 ar[RD];
#pragma unroll
            for (int r = 0; r < RD; ++r) {
                f32x4 z = {0.f, 0.f, 0.f, 0.f};
                z = MFMA16(aqp[r][0], bk0, z);
                z = MFMA16(aqp[r][1], bk1, z);
                ar[r] = z;
            }

            uchar4 a4 = *(const uchar4*)(adjrow + (size_t)jcol * 4);
            unsigned int bbits[4] = {a4.x, a4.y, a4.z, a4.w};
            float mkL = maskrow[jcol] * L2E;
#pragma unroll
            for (int reg = 0; reg < 4; ++reg) {
                float s = aqk[reg];
                unsigned int bt = bbits[reg];
#pragma unroll
                for (int r = 0; r < RD; ++r)
                    s = fmaf((float)((bt >> r) & 1u), ar[r][reg], s);
                sc[js][reg] = fmaf(s, SCL, lut[bt] + mkL);
            }
        }

        // ---- online softmax (exp2 domain; rows in 16-lane groups) ----
        float alpha[4];
#pragma unroll
        for (int reg = 0; reg < 4; ++reg) {
            float nm = fmaxf(fmaxf(sc[0][reg], sc[1][reg]),
                             fmaxf(sc[2][reg], sc[3][reg]));
#pragma unroll
            for (int off = 1; off < 16; off <<= 1)
                nm = fmaxf(nm, __shfl_xor(nm, off));
            float mn = fmaxf(mrun[reg], nm);
            alpha[reg] = exp2fast(mrun[reg] - mn);
            mrun[reg] = mn;
        }
#pragma unroll
        for (int js = 0; js < 4; ++js)
#pragma unroll
            for (int reg = 0; reg < 4; ++reg) {
                float p = exp2fast(sc[js][reg] - mrun[reg]);
                Pw[(quad * 4 + reg) * 72 + js * 16 + l15] = (f16)p;
            }
#pragma unroll
        for (int reg = 0; reg < 4; ++reg) {
            lacc[reg] *= alpha[reg];
#pragma unroll
            for (int ds = 0; ds < 4; ++ds) o[ds][reg] *= alpha[reg];
        }

        // ---- PV + row-sum via MFMA ----
        f16x8 pa0 = *(const f16x8*)&Pw[l15 * 72 + quad * 8];
        f16x8 pa1 = *(const f16x8*)&Pw[l15 * 72 + quad * 8 + 32];
        lacc = MFMA16(pa0, ones, lacc);
        lacc = MFMA16(pa1, ones, lacc);
#pragma unroll
        for (int ds = 0; ds < 4; ++ds) {
            const f16* vp = vtb + (size_t)(ds * 16 + l15) * S_ + j0 + quad * 8;
            f16x8 bv0 = *(const f16x8*)(vp);
            f16x8 bv1 = *(const f16x8*)(vp + 32);
            o[ds] = MFMA16(pa0, bv0, o[ds]);
            o[ds] = MFMA16(pa1, bv1, o[ds]);
        }
    }

    // ---- epilogue ----
#pragma unroll
    for (int reg = 0; reg < 4; ++reg) {
        float inv = 1.f / lacc[reg];
        int i = wi0 + quad * 4 + reg;
#pragma unroll
        for (int ds = 0; ds < 4; ++ds)
            out[((size_t)b * S_ + i) * H_ + n * DH + ds * 16 + l15] =
                o[ds][reg] * inv;
    }
}

// ---------------------------------------------------------------------------
extern "C" void kernel_launch(void* const* d_in, const int* in_sizes, int n_in,
                              void* d_out, int out_size, void* d_ws, size_t ws_size,
                              hipStream_t stream)
{
    const float* hs   = (const float*)d_in[0];
    const float* mask = (const float*)d_in[1];
    const float* adj  = (const float*)d_in[2];
    const float* Wq   = (const float*)d_in[3];
    const float* bq   = (const float*)d_in[4];
    const float* Wk   = (const float*)d_in[5];
    const float* bk   = (const float*)d_in[6];
    const float* Wv   = (const float*)d_in[7];
    const float* bv   = (const float*)d_in[8];
    const float* bili = (const float*)d_in[9];
    const float* absb = (const float*)d_in[10];
    float* out = (float*)d_out;

    const size_t QKV = (size_t)BN * S_ * DH;       // 3.1M elems
    f16* q  = (f16*)d_ws;
    f16* k  = q + QKV;
    f16* vt = k + QKV;
    unsigned char* adjp = (unsigned char*)(vt + QKV);       // 8 MB
    f16* xh = (f16*)(adjp + (size_t)B_ * 512 * S_ * 4);
    f16* wh = xh + (size_t)B_ * S_ * H_;                    // Wq|Wk|Wv f16

    const int total4 = NX4 + 3 * NW4;
    cvtall<<<(total4 + 255) / 256, 256, 0, stream>>>(hs, Wq, Wk, Wv, xh, wh);
    qkv_gemm<<<dim3(12, 64), 256, 0, stream>>>(xh, wh, bq, bk, bv, q, k, vt);
    adjpack<<<8192, 256, 0, stream>>>(adj, adjp);
    attn<<<768, 256, 0, stream>>>(q, k, vt, bili, adjp, mask, absb, out);
}